// Round 8
// baseline (387.365 us; speedup 1.0000x reference)
//
#include <hip/hip_runtime.h>

#define NPTS 16384
#define KNN 16
#define HID 64
#define NCLS 10

#define CHUNKS_T 16
#define CHUNK_T (NPTS / CHUNKS_T)   // 1024
#define NSTR 16                     // streams for tau bound
#define CHUNKS_S 16
#define CHUNK_S (NPTS / CHUNKS_S)   // 1024
#define CAPS 16                     // survivor slots per (query, chunk)

// distance helper: identical fmaf chain in every kernel so τ comparisons are
// bit-exact across passes (drop sq_i: rank-invariant per query)
__device__ __forceinline__ float distf(float4 q, float4 p) {
    float dot = fmaf(q.x, p.x, fmaf(q.y, p.y, q.z * p.z));
    return fmaf(-2.f, dot, p.w);
}

// monotone float->u32, packed with index: ascending u64 order == (d asc, j asc)
__device__ __forceinline__ unsigned long long dkey(float v, int j) {
    unsigned u = __float_as_uint(v);
    u = (u & 0x80000000u) ? ~u : (u | 0x80000000u);
    return ((unsigned long long)u << 32) | (unsigned)j;
}

__device__ __forceinline__ unsigned long long shfl_xor_u64(unsigned long long x, int m) {
    unsigned hi = (unsigned)__shfl_xor((int)(x >> 32), m, 64);
    unsigned lo = (unsigned)__shfl_xor((int)(x & 0xffffffffu), m, 64);
    return ((unsigned long long)hi << 32) | lo;
}

// exact wave-wide top-16 (overflow slow path only)
template <int NS>
__device__ __forceinline__ void wave_top16(unsigned long long (&key)[NS], int lane,
                                           int q, int* __restrict__ idx) {
    int outj = 0x7fffffff;
    for (int r = 0; r < 16; ++r) {
        unsigned long long gm = key[0];
#pragma unroll
        for (int s = 1; s < NS; ++s) gm = key[s] < gm ? key[s] : gm;
#pragma unroll
        for (int st = 1; st < 64; st <<= 1) {
            unsigned long long o = shfl_xor_u64(gm, st);
            gm = o < gm ? o : gm;
        }
        if (lane == r) outj = (int)(gm & 0xffffffffu);
#pragma unroll
        for (int s = 0; s < NS; ++s)
            if (key[s] == gm) key[s] = ~0ull;
    }
    if (lane < 16) idx[q * KNN + lane] = outj;
}

// pos (N,3) -> pos4 (x,y,z,|p|^2)
__global__ void prep_kernel(const float* __restrict__ pos, float4* __restrict__ pos4) {
    int i = blockIdx.x * 256 + threadIdx.x;
    if (i < NPTS) {
        float x = pos[3 * i], y = pos[3 * i + 1], z = pos[3 * i + 2];
        pos4[i] = make_float4(x, y, z, fmaf(x, x, fmaf(y, y, z * z)));
    }
}

// Pass 1: NSTR stream minima per (query, chunk); 2 queries/thread, 512 blocks.
__global__ __launch_bounds__(256) void knn_tau_kernel(const float4* __restrict__ pos4,
                                                      float* __restrict__ minpart) {
    int tid = threadIdx.x;
    int q0 = blockIdx.x * 512 + tid;
    int q1 = q0 + 256;
    int c = blockIdx.y;
    float4 qa = pos4[q0];
    float4 qb = pos4[q1];
    float mna[NSTR], mnb[NSTR];
#pragma unroll
    for (int u = 0; u < NSTR; ++u) { mna[u] = INFINITY; mnb[u] = INFINITY; }
    __shared__ float4 tile[256];
    int base = c * CHUNK_T;
    for (int t0 = 0; t0 < CHUNK_T; t0 += 256) {
        __syncthreads();
        tile[tid] = pos4[base + t0 + tid];
        __syncthreads();
        for (int jj = 0; jj < 256; jj += NSTR) {
#pragma unroll
            for (int u = 0; u < NSTR; ++u) {
                float4 p = tile[jj + u];
                mna[u] = fminf(mna[u], distf(qa, p));
                mnb[u] = fminf(mnb[u], distf(qb, p));
            }
        }
    }
#pragma unroll
    for (int u = 0; u < NSTR; ++u) {
        minpart[(c * NSTR + u) * NPTS + q0] = mna[u];
        minpart[(c * NSTR + u) * NPTS + q1] = mnb[u];
    }
}

// tau[q] = max over the 16 global stream minima; >= d_16(q) (16 distinct argmins).
__global__ __launch_bounds__(256) void knn_tau_reduce_kernel(const float* __restrict__ minpart,
                                                             float* __restrict__ tau) {
    int q = blockIdx.x * 256 + threadIdx.x;
    float t = -INFINITY;
#pragma unroll
    for (int u = 0; u < NSTR; ++u) {
        float m = INFINITY;
#pragma unroll
        for (int c = 0; c < CHUNKS_T; ++c) m = fminf(m, minpart[(c * NSTR + u) * NPTS + q]);
        t = fmaxf(t, m);
    }
    tau[q] = t;
}

// Pass 2: record tau-survivor KEYS (d,j packed u64) per (query, chunk).
// Final pass then needs no gather and no distance recompute.
__global__ __launch_bounds__(256) void knn_survey_kernel(const float4* __restrict__ pos4,
                                                         const float* __restrict__ tau,
                                                         unsigned long long* __restrict__ surv,
                                                         int* __restrict__ cnt,
                                                         int* __restrict__ flags) {
    int tid = threadIdx.x;
    int q = blockIdx.x * 256 + tid;
    int c = blockIdx.y;
    float4 qp = pos4[q];
    float tq = tau[q];
    __shared__ float4 tile[256];
    int base = c * CHUNK_S;
    int cr = 0;
    int sbase = (q * CHUNKS_S + c) * CAPS;
    for (int t0 = 0; t0 < CHUNK_S; t0 += 256) {
        __syncthreads();
        tile[tid] = pos4[base + t0 + tid];
        __syncthreads();
#pragma unroll 4
        for (int jj = 0; jj < 256; ++jj) {
            float v = distf(qp, tile[jj]);
            if (v <= tq) {
                if (cr < CAPS) surv[sbase + cr] = dkey(v, base + t0 + jj);
                ++cr;
            }
        }
    }
    cnt[q * CHUNKS_S + c] = cr;
    if (cr > CAPS) flags[q] = 1;   // overflow -> exact rescan in final
}

// Pass 3: wave-per-query LDS rank-select over precomputed keys. One round of
// independent coalesced loads (no gather chain), then compaction + rank sweep.
__global__ __launch_bounds__(256) void knn_final_kernel(const float4* __restrict__ pos4,
                                                        const unsigned long long* __restrict__ surv,
                                                        const int* __restrict__ cnt,
                                                        const int* __restrict__ flags,
                                                        const float* __restrict__ tau,
                                                        int* __restrict__ idx) {
    __shared__ unsigned long long buf[4][CHUNKS_S * CAPS];
    __shared__ int nbuf[4];
    int lane = threadIdx.x & 63;
    int w = threadIdx.x >> 6;
    int q = blockIdx.x * 4 + w;
    if (lane == 0) nbuf[w] = 0;
    if (flags[q] == 0) {
        int c = lane & 15;
        int sb = lane >> 4;                     // 0..3
        int n = min(cnt[q * CHUNKS_S + c], CAPS);
        int sbase = (q * CHUNKS_S + c) * CAPS;
        int nv = n - sb;
        int nk = nv > 0 ? (nv + 3) >> 2 : 0;    // # of my slots (sb, sb+4, ...) < n; <= 4
        unsigned long long key[4];
#pragma unroll
        for (int r = 0; r < 4; ++r)
            key[r] = (r < nk) ? surv[sbase + sb + 4 * r] : ~0ull;
        int pos = atomicAdd(&nbuf[w], nk);
#pragma unroll
        for (int r = 0; r < 4; ++r)
            if (r < nk) buf[w][pos + r] = key[r];
        int ntot = atomicAdd(&nbuf[w], 0);      // wave-lockstep: all adds retired
        int rank[4];
#pragma unroll
        for (int r = 0; r < 4; ++r) rank[r] = 0;
        for (int t = 0; t < ntot; ++t) {
            unsigned long long k = buf[w][t];   // broadcast ds_read
#pragma unroll
            for (int r = 0; r < 4; ++r) rank[r] += (int)(r < nk && k < key[r]);
        }
#pragma unroll
        for (int r = 0; r < 4; ++r)
            if (r < nk && rank[r] < 16) idx[q * KNN + rank[r]] = (int)(key[r] & 0xffffffffu);
    } else {
        // overflow slow path: wave-cooperative exact rescan (rare, data-dependent)
        float4 qp = pos4[q];
        float tq = tau[q];
        unsigned long long key[16];
#pragma unroll
        for (int u = 0; u < 16; ++u) key[u] = ~0ull;
        for (int j = lane; j < NPTS; j += 64) {
            float v = distf(qp, pos4[j]);
            unsigned long long k = dkey(v, j);
            if (v <= tq && k < key[15]) {
#pragma unroll
                for (int s = 0; s < 16; ++s) {
                    unsigned long long mn = k < key[s] ? k : key[s];
                    unsigned long long mx = k < key[s] ? key[s] : k;
                    key[s] = mn;
                    k = mx;
                }
            }
        }
        wave_top16<16>(key, lane, q, idx);
    }
}

// EdgeConv factorization: m[k][t] = C[i][t] + Y[j][t]; max commutes with +C.

// ec1_pre: C1[p][t] = b1 + x·(W1a-W1b) ; Y1[p][t] = x·W1b
__global__ __launch_bounds__(256) void ec1_pre_kernel(const float4* __restrict__ pos4,
                                                      const float* __restrict__ W1,
                                                      const float* __restrict__ b1,
                                                      float* __restrict__ C1,
                                                      float* __restrict__ Y1) {
    int t = threadIdx.x & 63;
    int p = blockIdx.x * 4 + (threadIdx.x >> 6);
    float4 x = pos4[p];
    float w0 = W1[0 * HID + t], w1 = W1[1 * HID + t], w2 = W1[2 * HID + t];
    float v0 = W1[3 * HID + t], v1 = W1[4 * HID + t], v2 = W1[5 * HID + t];
    float y = fmaf(x.x, v0, fmaf(x.y, v1, x.z * v2));
    float cc = b1[t] + x.x * (w0 - v0) + x.y * (w1 - v1) + x.z * (w2 - v2);
    Y1[p * HID + t] = y;
    C1[p * HID + t] = cc;
}

// ec1_max: h1[p][t] = relu(C1[p][t] + max_k Y1[idx[p][k]][t])
__global__ __launch_bounds__(256) void ec1_max_kernel(const float* __restrict__ C1,
                                                      const float* __restrict__ Y1,
                                                      const int* __restrict__ idx,
                                                      float* __restrict__ h1) {
    int t = threadIdx.x & 63;
    int p = blockIdx.x * 4 + (threadIdx.x >> 6);
    float m = -INFINITY;
#pragma unroll
    for (int k = 0; k < KNN; ++k) {
        int j = idx[p * KNN + k];
        m = fmaxf(m, Y1[j * HID + t]);
    }
    h1[p * HID + t] = fmaxf(C1[p * HID + t] + m, 0.f);
}

// ec2_pre: C2[p][t] = b2 + h1[p]·(W2a-W2b) ; Y2[p][t] = h1[p]·W2b
__global__ __launch_bounds__(256) void ec2_pre_kernel(const float* __restrict__ h1,
                                                      const float* __restrict__ W2,
                                                      const float* __restrict__ b2,
                                                      float* __restrict__ C2,
                                                      float* __restrict__ Y2) {
    int t = threadIdx.x & 63;
    int r = threadIdx.x >> 6;            // 0..3
    int pb = blockIdx.x * 16 + r * 4;
    float aa[4] = {0.f, 0.f, 0.f, 0.f};
    float ab[4] = {0.f, 0.f, 0.f, 0.f};
#pragma unroll 8
    for (int f = 0; f < 64; ++f) {
        float wa = W2[f * HID + t];
        float wb = W2[(64 + f) * HID + t];
#pragma unroll
        for (int i = 0; i < 4; ++i) {
            float h = h1[(pb + i) * HID + f];   // wave-uniform broadcast
            aa[i] = fmaf(h, wa, aa[i]);
            ab[i] = fmaf(h, wb, ab[i]);
        }
    }
    float bt = b2[t];
#pragma unroll
    for (int i = 0; i < 4; ++i) {
        C2[(pb + i) * HID + t] = bt + aa[i] - ab[i];
        Y2[(pb + i) * HID + t] = ab[i];
    }
}

// ec2_maxpool: val = relu(C2 + max_k Y2[idx[k]]); block-partial max-pool.
__global__ __launch_bounds__(256) void ec2_maxpool_kernel(const float* __restrict__ C2,
                                                          const float* __restrict__ Y2,
                                                          const int* __restrict__ idx,
                                                          float* __restrict__ gpartial) {
    int t = threadIdx.x & 63;
    int lp = threadIdx.x >> 6;
    int p = blockIdx.x * 4 + lp;
    float m = -INFINITY;
#pragma unroll
    for (int k = 0; k < KNN; ++k) {
        int j = idx[p * KNN + k];
        m = fmaxf(m, Y2[j * HID + t]);
    }
    float val = fmaxf(C2[p * HID + t] + m, 0.f);
    __shared__ float red[4][64];
    red[lp][t] = val;
    __syncthreads();
    if (lp == 0) {
        float g = fmaxf(fmaxf(red[0][t], red[1][t]), fmaxf(red[2][t], red[3][t]));
        gpartial[blockIdx.x * 64 + t] = g;
    }
}

// greduce2: 4096 -> 256 partial rows, fully coalesced, 256 parallel blocks.
__global__ __launch_bounds__(256) void greduce2_kernel(const float* __restrict__ gpartial,
                                                       float* __restrict__ gp2) {
    __shared__ float red[4][64];
    int f = threadIdx.x & 63;
    int w = threadIdx.x >> 6;
    int r0 = blockIdx.x * 16 + w * 4;
    float m = -INFINITY;
#pragma unroll
    for (int r = 0; r < 4; ++r) m = fmaxf(m, gpartial[(r0 + r) * 64 + f]);
    red[w][f] = m;
    __syncthreads();
    if (w == 0)
        gp2[blockIdx.x * 64 + f] =
            fmaxf(fmaxf(red[0][f], red[1][f]), fmaxf(red[2][f], red[3][f]));
}

// tail2: 256 rows -> g[64], then linear head. One block (cheap now).
__global__ __launch_bounds__(256) void tail2_kernel(const float* __restrict__ gp2,
                                                    const float* __restrict__ Wc,
                                                    const float* __restrict__ bc,
                                                    float* __restrict__ out) {
    __shared__ float red[4][64];
    __shared__ float g[64];
    int f = threadIdx.x & 63;
    int w = threadIdx.x >> 6;
    float m = -INFINITY;
    for (int i = w; i < 256; i += 4) m = fmaxf(m, gp2[i * 64 + f]);
    red[w][f] = m;
    __syncthreads();
    if (w == 0) g[f] = fmaxf(fmaxf(red[0][f], red[1][f]), fmaxf(red[2][f], red[3][f]));
    __syncthreads();
    if (threadIdx.x < NCLS) {
        float a = bc[threadIdx.x];
#pragma unroll
        for (int h = 0; h < HID; ++h) a = fmaf(g[h], Wc[h * NCLS + threadIdx.x], a);
        out[threadIdx.x] = a;
    }
}

extern "C" void kernel_launch(void* const* d_in, const int* in_sizes, int n_in,
                              void* d_out, int out_size, void* d_ws, size_t ws_size,
                              hipStream_t stream) {
    const float* pos = (const float*)d_in[0];
    // d_in[1] = batch (all zeros, num_segments=1) -> unused
    const float* W1 = (const float*)d_in[2];
    const float* b1 = (const float*)d_in[3];
    const float* W2 = (const float*)d_in[4];
    const float* b2 = (const float*)d_in[5];
    const float* Wc = (const float*)d_in[6];
    const float* bc = (const float*)d_in[7];
    float* out = (float*)d_out;

    char* ws = (char*)d_ws;
    size_t o = 0;
    auto alloc = [&](size_t bytes) { size_t r = o; o += (bytes + 255) & ~size_t(255); return r; };
    size_t sz_minp = (size_t)NPTS * CHUNKS_T * NSTR * 4;      // 16.8MB
    size_t sz_surv = (size_t)NPTS * CHUNKS_S * CAPS * 8;      // 33.6MB (u64 keys)
    size_t o_pos4 = alloc((size_t)NPTS * 16);
    size_t o_shared = alloc(sz_minp > sz_surv ? sz_minp : sz_surv);  // minp -> surv -> C/Y
    size_t o_tau = alloc((size_t)NPTS * 4);
    size_t o_cnt = alloc((size_t)NPTS * CHUNKS_S * 4);        // 1MB
    size_t o_flag = alloc((size_t)NPTS * 4);
    size_t o_idx = alloc((size_t)NPTS * KNN * 4);
    size_t o_h1 = alloc((size_t)NPTS * HID * 4);
    size_t o_gp = alloc((size_t)(NPTS / 4) * HID * 4);
    size_t o_gp2 = alloc((size_t)256 * HID * 4);

    float4* pos4 = (float4*)(ws + o_pos4);
    float* minp = (float*)(ws + o_shared);
    unsigned long long* surv = (unsigned long long*)(ws + o_shared);  // overlays minp
    // C1/Y1/C2/Y2 overlay surv (dead after knn_final): 4 x 4.2MB <= 33.6MB region
    size_t fm = (size_t)NPTS * HID * 4;
    float* C1 = (float*)(ws + o_shared + 0 * fm);
    float* Y1 = (float*)(ws + o_shared + 1 * fm);
    float* C2 = (float*)(ws + o_shared + 2 * fm);
    float* Y2 = (float*)(ws + o_shared + 3 * fm);
    float* tau = (float*)(ws + o_tau);
    int* cnt = (int*)(ws + o_cnt);
    int* flags = (int*)(ws + o_flag);
    int* idx = (int*)(ws + o_idx);
    float* h1 = (float*)(ws + o_h1);
    float* gp = (float*)(ws + o_gp);
    float* gp2 = (float*)(ws + o_gp2);

    hipMemsetAsync(flags, 0, (size_t)NPTS * 4, stream);

    prep_kernel<<<NPTS / 256, 256, 0, stream>>>(pos, pos4);
    knn_tau_kernel<<<dim3(NPTS / 512, CHUNKS_T), 256, 0, stream>>>(pos4, minp);
    knn_tau_reduce_kernel<<<NPTS / 256, 256, 0, stream>>>(minp, tau);
    knn_survey_kernel<<<dim3(NPTS / 256, CHUNKS_S), 256, 0, stream>>>(pos4, tau, surv, cnt, flags);
    knn_final_kernel<<<NPTS / 4, 256, 0, stream>>>(pos4, surv, cnt, flags, tau, idx);
    ec1_pre_kernel<<<NPTS / 4, 256, 0, stream>>>(pos4, W1, b1, C1, Y1);
    ec1_max_kernel<<<NPTS / 4, 256, 0, stream>>>(C1, Y1, idx, h1);
    ec2_pre_kernel<<<NPTS / 16, 256, 0, stream>>>(h1, W2, b2, C2, Y2);
    ec2_maxpool_kernel<<<NPTS / 4, 256, 0, stream>>>(C2, Y2, idx, gp);
    greduce2_kernel<<<256, 256, 0, stream>>>(gp, gp2);
    tail2_kernel<<<1, 256, 0, stream>>>(gp2, Wc, bc, out);
}

// Round 9
// 342.739 us; speedup vs baseline: 1.1302x; 1.1302x over previous
//
#include <hip/hip_runtime.h>

#define NPTS 16384
#define KNN 16
#define HID 64
#define NCLS 10

#define CHUNKS_T 16
#define CHUNK_T (NPTS / CHUNKS_T)   // 1024
#define NSTR 16                     // streams for tau bound
#define SCAP 128                    // per-query survivor capacity (LDS list)

// distance helper: identical fmaf chain in every kernel so τ comparisons are
// bit-exact across passes (drop sq_i: rank-invariant per query)
__device__ __forceinline__ float distf(float4 q, float4 p) {
    float dot = fmaf(q.x, p.x, fmaf(q.y, p.y, q.z * p.z));
    return fmaf(-2.f, dot, p.w);
}

// monotone float->u32, packed with index: ascending u64 order == (d asc, j asc)
__device__ __forceinline__ unsigned long long dkey(float v, int j) {
    unsigned u = __float_as_uint(v);
    u = (u & 0x80000000u) ? ~u : (u | 0x80000000u);
    return ((unsigned long long)u << 32) | (unsigned)j;
}

__device__ __forceinline__ unsigned long long shfl_xor_u64(unsigned long long x, int m) {
    unsigned hi = (unsigned)__shfl_xor((int)(x >> 32), m, 64);
    unsigned lo = (unsigned)__shfl_xor((int)(x & 0xffffffffu), m, 64);
    return ((unsigned long long)hi << 32) | lo;
}

// exact wave-wide top-16 (overflow slow path only)
__device__ __forceinline__ void wave_top16_16(unsigned long long (&key)[16], int lane,
                                              int q, int* __restrict__ idx) {
    int outj = 0x7fffffff;
    for (int r = 0; r < 16; ++r) {
        unsigned long long gm = key[0];
#pragma unroll
        for (int s = 1; s < 16; ++s) gm = key[s] < gm ? key[s] : gm;
#pragma unroll
        for (int st = 1; st < 64; st <<= 1) {
            unsigned long long o = shfl_xor_u64(gm, st);
            gm = o < gm ? o : gm;
        }
        if (lane == r) outj = (int)(gm & 0xffffffffu);
#pragma unroll
        for (int s = 0; s < 16; ++s)
            if (key[s] == gm) key[s] = ~0ull;
    }
    if (lane < 16) idx[q * KNN + lane] = outj;
}

// pos (N,3) -> pos4 (x,y,z,|p|^2)
__global__ void prep_kernel(const float* __restrict__ pos, float4* __restrict__ pos4) {
    int i = blockIdx.x * 256 + threadIdx.x;
    if (i < NPTS) {
        float x = pos[3 * i], y = pos[3 * i + 1], z = pos[3 * i + 2];
        pos4[i] = make_float4(x, y, z, fmaf(x, x, fmaf(y, y, z * z)));
    }
}

// Pass 1: NSTR stream minima per (query, chunk); 2 queries/thread, 512 blocks.
__global__ __launch_bounds__(256) void knn_tau_kernel(const float4* __restrict__ pos4,
                                                      float* __restrict__ minpart) {
    int tid = threadIdx.x;
    int q0 = blockIdx.x * 512 + tid;
    int q1 = q0 + 256;
    int c = blockIdx.y;
    float4 qa = pos4[q0];
    float4 qb = pos4[q1];
    float mna[NSTR], mnb[NSTR];
#pragma unroll
    for (int u = 0; u < NSTR; ++u) { mna[u] = INFINITY; mnb[u] = INFINITY; }
    __shared__ float4 tile[256];
    int base = c * CHUNK_T;
    for (int t0 = 0; t0 < CHUNK_T; t0 += 256) {
        __syncthreads();
        tile[tid] = pos4[base + t0 + tid];
        __syncthreads();
        for (int jj = 0; jj < 256; jj += NSTR) {
#pragma unroll
            for (int u = 0; u < NSTR; ++u) {
                float4 p = tile[jj + u];
                mna[u] = fminf(mna[u], distf(qa, p));
                mnb[u] = fminf(mnb[u], distf(qb, p));
            }
        }
    }
#pragma unroll
    for (int u = 0; u < NSTR; ++u) {
        minpart[(c * NSTR + u) * NPTS + q0] = mna[u];
        minpart[(c * NSTR + u) * NPTS + q1] = mnb[u];
    }
}

// tau[q] = max over the 16 global stream minima; >= d_16(q) (16 distinct argmins).
__global__ __launch_bounds__(256) void knn_tau_reduce_kernel(const float* __restrict__ minpart,
                                                             float* __restrict__ tau) {
    int q = blockIdx.x * 256 + threadIdx.x;
    float t = -INFINITY;
#pragma unroll
    for (int u = 0; u < NSTR; ++u) {
        float m = INFINITY;
#pragma unroll
        for (int c = 0; c < CHUNKS_T; ++c) m = fminf(m, minpart[(c * NSTR + u) * NPTS + q]);
        t = fmaxf(t, m);
    }
    tau[q] = t;
}

// Fused survey+select: block = 4 waves x 4 queries/wave. One pass over all
// candidates via LDS tile; tau-survivor keys pushed to per-query LDS lists
// (wave-private, no global round-trip); in-LDS rank-select writes idx.
__global__ __launch_bounds__(256) void knn_fused_kernel(const float4* __restrict__ pos4,
                                                        const float* __restrict__ tau,
                                                        int* __restrict__ idx) {
    __shared__ float4 tile[256];
    __shared__ unsigned long long keys[16][SCAP];   // 16KB
    __shared__ int knt[16];
    int tid = threadIdx.x;
    int lane = tid & 63;
    int w = tid >> 6;
    int qb = blockIdx.x * 16 + w * 4;
    float4 qp0 = pos4[qb + 0], qp1 = pos4[qb + 1], qp2 = pos4[qb + 2], qp3 = pos4[qb + 3];
    float tq0 = tau[qb + 0], tq1 = tau[qb + 1], tq2 = tau[qb + 2], tq3 = tau[qb + 3];
    if (lane < 4) knt[w * 4 + lane] = 0;   // wave-private slots; same-wave LDS order
    for (int tb = 0; tb < NPTS; tb += 256) {
        __syncthreads();
        tile[tid] = pos4[tb + tid];
        __syncthreads();
#pragma unroll
        for (int r = 0; r < 4; ++r) {
            int jj = r * 64 + lane;
            float4 p = tile[jj];
            int j = tb + jj;
            float v0 = distf(qp0, p);
            float v1 = distf(qp1, p);
            float v2 = distf(qp2, p);
            float v3 = distf(qp3, p);
            if (v0 <= tq0) { int s = atomicAdd(&knt[w * 4 + 0], 1); if (s < SCAP) keys[w * 4 + 0][s] = dkey(v0, j); }
            if (v1 <= tq1) { int s = atomicAdd(&knt[w * 4 + 1], 1); if (s < SCAP) keys[w * 4 + 1][s] = dkey(v1, j); }
            if (v2 <= tq2) { int s = atomicAdd(&knt[w * 4 + 2], 1); if (s < SCAP) keys[w * 4 + 2][s] = dkey(v2, j); }
            if (v3 <= tq3) { int s = atomicAdd(&knt[w * 4 + 3], 1); if (s < SCAP) keys[w * 4 + 3][s] = dkey(v3, j); }
        }
    }
    // extraction: wave-private lists, no block barrier needed.
#pragma unroll
    for (int qi = 0; qi < 4; ++qi) {
        int q = qb + qi;
        int ntot = knt[w * 4 + qi];          // ordered after this wave's own atomics
        if (ntot <= SCAP) {
            // ntot >= 16 always (tau >= d16). Rank-select: ranks 0..15 unique.
            unsigned long long k0 = (lane < ntot) ? keys[w * 4 + qi][lane] : ~0ull;
            unsigned long long k1 = (lane + 64 < ntot) ? keys[w * 4 + qi][lane + 64] : ~0ull;
            int r0 = 0, r1 = 0;
            for (int t = 0; t < ntot; ++t) {
                unsigned long long k = keys[w * 4 + qi][t];   // broadcast ds_read
                r0 += (int)(k < k0);
                r1 += (int)(k < k1);
            }
            if (lane < ntot && r0 < KNN) idx[q * KNN + r0] = (int)(k0 & 0xffffffffu);
            if (lane + 64 < ntot && r1 < KNN) idx[q * KNN + r1] = (int)(k1 & 0xffffffffu);
        } else {
            // overflow (ntot>SCAP, ~+10 sigma): exact wave-cooperative rescan
            float tq = tau[q];
            float4 qq = pos4[q];
            unsigned long long key[16];
#pragma unroll
            for (int u = 0; u < 16; ++u) key[u] = ~0ull;
            for (int j = lane; j < NPTS; j += 64) {
                float v = distf(qq, pos4[j]);
                unsigned long long k = dkey(v, j);
                if (v <= tq && k < key[15]) {
#pragma unroll
                    for (int s = 0; s < 16; ++s) {
                        unsigned long long mn = k < key[s] ? k : key[s];
                        unsigned long long mx = k < key[s] ? key[s] : k;
                        key[s] = mn;
                        k = mx;
                    }
                }
            }
            wave_top16_16(key, lane, q, idx);
        }
    }
}

// EdgeConv factorization: m[k][t] = C[i][t] + Y[j][t]; max commutes with +C.

// ec1_pre: C1[p][t] = b1 + x·(W1a-W1b) ; Y1[p][t] = x·W1b
__global__ __launch_bounds__(256) void ec1_pre_kernel(const float4* __restrict__ pos4,
                                                      const float* __restrict__ W1,
                                                      const float* __restrict__ b1,
                                                      float* __restrict__ C1,
                                                      float* __restrict__ Y1) {
    int t = threadIdx.x & 63;
    int p = blockIdx.x * 4 + (threadIdx.x >> 6);
    float4 x = pos4[p];
    float w0 = W1[0 * HID + t], w1 = W1[1 * HID + t], w2 = W1[2 * HID + t];
    float v0 = W1[3 * HID + t], v1 = W1[4 * HID + t], v2 = W1[5 * HID + t];
    float y = fmaf(x.x, v0, fmaf(x.y, v1, x.z * v2));
    float cc = b1[t] + x.x * (w0 - v0) + x.y * (w1 - v1) + x.z * (w2 - v2);
    Y1[p * HID + t] = y;
    C1[p * HID + t] = cc;
}

// ec1_max: h1[p][t] = relu(C1[p][t] + max_k Y1[idx[p][k]][t])
__global__ __launch_bounds__(256) void ec1_max_kernel(const float* __restrict__ C1,
                                                      const float* __restrict__ Y1,
                                                      const int* __restrict__ idx,
                                                      float* __restrict__ h1) {
    int t = threadIdx.x & 63;
    int p = blockIdx.x * 4 + (threadIdx.x >> 6);
    float m = -INFINITY;
#pragma unroll
    for (int k = 0; k < KNN; ++k) {
        int j = idx[p * KNN + k];
        m = fmaxf(m, Y1[j * HID + t]);
    }
    h1[p * HID + t] = fmaxf(C1[p * HID + t] + m, 0.f);
}

// ec2_pre: C2[p][t] = b2 + h1[p]·(W2a-W2b) ; Y2[p][t] = h1[p]·W2b
__global__ __launch_bounds__(256) void ec2_pre_kernel(const float* __restrict__ h1,
                                                      const float* __restrict__ W2,
                                                      const float* __restrict__ b2,
                                                      float* __restrict__ C2,
                                                      float* __restrict__ Y2) {
    int t = threadIdx.x & 63;
    int r = threadIdx.x >> 6;            // 0..3
    int pb = blockIdx.x * 16 + r * 4;
    float aa[4] = {0.f, 0.f, 0.f, 0.f};
    float ab[4] = {0.f, 0.f, 0.f, 0.f};
#pragma unroll 8
    for (int f = 0; f < 64; ++f) {
        float wa = W2[f * HID + t];
        float wb = W2[(64 + f) * HID + t];
#pragma unroll
        for (int i = 0; i < 4; ++i) {
            float h = h1[(pb + i) * HID + f];   // wave-uniform broadcast
            aa[i] = fmaf(h, wa, aa[i]);
            ab[i] = fmaf(h, wb, ab[i]);
        }
    }
    float bt = b2[t];
#pragma unroll
    for (int i = 0; i < 4; ++i) {
        C2[(pb + i) * HID + t] = bt + aa[i] - ab[i];
        Y2[(pb + i) * HID + t] = ab[i];
    }
}

// ec2_maxpool: val = relu(C2 + max_k Y2[idx[k]]); block-partial max-pool.
__global__ __launch_bounds__(256) void ec2_maxpool_kernel(const float* __restrict__ C2,
                                                          const float* __restrict__ Y2,
                                                          const int* __restrict__ idx,
                                                          float* __restrict__ gpartial) {
    int t = threadIdx.x & 63;
    int lp = threadIdx.x >> 6;
    int p = blockIdx.x * 4 + lp;
    float m = -INFINITY;
#pragma unroll
    for (int k = 0; k < KNN; ++k) {
        int j = idx[p * KNN + k];
        m = fmaxf(m, Y2[j * HID + t]);
    }
    float val = fmaxf(C2[p * HID + t] + m, 0.f);
    __shared__ float red[4][64];
    red[lp][t] = val;
    __syncthreads();
    if (lp == 0) {
        float g = fmaxf(fmaxf(red[0][t], red[1][t]), fmaxf(red[2][t], red[3][t]));
        gpartial[blockIdx.x * 64 + t] = g;
    }
}

// greduce2: 4096 -> 256 partial rows, fully coalesced, 256 parallel blocks.
__global__ __launch_bounds__(256) void greduce2_kernel(const float* __restrict__ gpartial,
                                                       float* __restrict__ gp2) {
    __shared__ float red[4][64];
    int f = threadIdx.x & 63;
    int w = threadIdx.x >> 6;
    int r0 = blockIdx.x * 16 + w * 4;
    float m = -INFINITY;
#pragma unroll
    for (int r = 0; r < 4; ++r) m = fmaxf(m, gpartial[(r0 + r) * 64 + f]);
    red[w][f] = m;
    __syncthreads();
    if (w == 0)
        gp2[blockIdx.x * 64 + f] =
            fmaxf(fmaxf(red[0][f], red[1][f]), fmaxf(red[2][f], red[3][f]));
}

// tail2: 256 rows -> g[64], then linear head. One block (cheap now).
__global__ __launch_bounds__(256) void tail2_kernel(const float* __restrict__ gp2,
                                                    const float* __restrict__ Wc,
                                                    const float* __restrict__ bc,
                                                    float* __restrict__ out) {
    __shared__ float red[4][64];
    __shared__ float g[64];
    int f = threadIdx.x & 63;
    int w = threadIdx.x >> 6;
    float m = -INFINITY;
    for (int i = w; i < 256; i += 4) m = fmaxf(m, gp2[i * 64 + f]);
    red[w][f] = m;
    __syncthreads();
    if (w == 0) g[f] = fmaxf(fmaxf(red[0][f], red[1][f]), fmaxf(red[2][f], red[3][f]));
    __syncthreads();
    if (threadIdx.x < NCLS) {
        float a = bc[threadIdx.x];
#pragma unroll
        for (int h = 0; h < HID; ++h) a = fmaf(g[h], Wc[h * NCLS + threadIdx.x], a);
        out[threadIdx.x] = a;
    }
}

extern "C" void kernel_launch(void* const* d_in, const int* in_sizes, int n_in,
                              void* d_out, int out_size, void* d_ws, size_t ws_size,
                              hipStream_t stream) {
    const float* pos = (const float*)d_in[0];
    // d_in[1] = batch (all zeros, num_segments=1) -> unused
    const float* W1 = (const float*)d_in[2];
    const float* b1 = (const float*)d_in[3];
    const float* W2 = (const float*)d_in[4];
    const float* b2 = (const float*)d_in[5];
    const float* Wc = (const float*)d_in[6];
    const float* bc = (const float*)d_in[7];
    float* out = (float*)d_out;

    char* ws = (char*)d_ws;
    size_t o = 0;
    auto alloc = [&](size_t bytes) { size_t r = o; o += (bytes + 255) & ~size_t(255); return r; };
    size_t sz_minp = (size_t)NPTS * CHUNKS_T * NSTR * 4;      // 16.8MB
    size_t sz_cy = (size_t)NPTS * HID * 4 * 4;                // C1/Y1/C2/Y2 = 16.8MB
    size_t o_pos4 = alloc((size_t)NPTS * 16);
    size_t o_shared = alloc(sz_minp > sz_cy ? sz_minp : sz_cy);  // minp -> C/Y overlay
    size_t o_tau = alloc((size_t)NPTS * 4);
    size_t o_idx = alloc((size_t)NPTS * KNN * 4);
    size_t o_h1 = alloc((size_t)NPTS * HID * 4);
    size_t o_gp = alloc((size_t)(NPTS / 4) * HID * 4);
    size_t o_gp2 = alloc((size_t)256 * HID * 4);

    float4* pos4 = (float4*)(ws + o_pos4);
    float* minp = (float*)(ws + o_shared);
    // C1/Y1/C2/Y2 overlay minpart (dead after tau_reduce)
    size_t fm = (size_t)NPTS * HID * 4;
    float* C1 = (float*)(ws + o_shared + 0 * fm);
    float* Y1 = (float*)(ws + o_shared + 1 * fm);
    float* C2 = (float*)(ws + o_shared + 2 * fm);
    float* Y2 = (float*)(ws + o_shared + 3 * fm);
    float* tau = (float*)(ws + o_tau);
    int* idx = (int*)(ws + o_idx);
    float* h1 = (float*)(ws + o_h1);
    float* gp = (float*)(ws + o_gp);
    float* gp2 = (float*)(ws + o_gp2);

    prep_kernel<<<NPTS / 256, 256, 0, stream>>>(pos, pos4);
    knn_tau_kernel<<<dim3(NPTS / 512, CHUNKS_T), 256, 0, stream>>>(pos4, minp);
    knn_tau_reduce_kernel<<<NPTS / 256, 256, 0, stream>>>(minp, tau);
    knn_fused_kernel<<<NPTS / 16, 256, 0, stream>>>(pos4, tau, idx);
    ec1_pre_kernel<<<NPTS / 4, 256, 0, stream>>>(pos4, W1, b1, C1, Y1);
    ec1_max_kernel<<<NPTS / 4, 256, 0, stream>>>(C1, Y1, idx, h1);
    ec2_pre_kernel<<<NPTS / 16, 256, 0, stream>>>(h1, W2, b2, C2, Y2);
    ec2_maxpool_kernel<<<NPTS / 4, 256, 0, stream>>>(C2, Y2, idx, gp);
    greduce2_kernel<<<256, 256, 0, stream>>>(gp, gp2);
    tail2_kernel<<<1, 256, 0, stream>>>(gp2, Wc, bc, out);
}